// Round 1
// baseline (852.888 us; speedup 1.0000x reference)
//
#include <hip/hip_runtime.h>

// ---------------- degree / CSR construction ----------------

__global__ void count_k(const int* __restrict__ dst, int* __restrict__ cnt, int E) {
    int e = blockIdx.x * blockDim.x + threadIdx.x;
    if (e < E) atomicAdd(&cnt[dst[e]], 1);
}

__global__ void dinv_k(const int* __restrict__ cnt, float* __restrict__ dinv, int N) {
    int i = blockIdx.x * blockDim.x + threadIdx.x;
    if (i < N) dinv[i] = rsqrtf((float)cnt[i] + 1.0f);
}

__global__ void scan1(const int* __restrict__ cnt, int* __restrict__ incl,
                      int* __restrict__ bsum, int n) {
    __shared__ int tmp[256];
    int t = threadIdx.x;
    int gid = blockIdx.x * 256 + t;
    tmp[t] = (gid < n) ? cnt[gid] : 0;
    __syncthreads();
    for (int off = 1; off < 256; off <<= 1) {
        int v = (t >= off) ? tmp[t - off] : 0;
        __syncthreads();
        tmp[t] += v;
        __syncthreads();
    }
    if (gid < n) incl[gid] = tmp[t];
    if (t == 255) bsum[blockIdx.x] = tmp[255];
}

__global__ void scan2(const int* __restrict__ bsum, int* __restrict__ boff, int nb) {
    __shared__ int tmp[512];
    int t = threadIdx.x;
    int orig = (t < nb) ? bsum[t] : 0;
    tmp[t] = orig;
    __syncthreads();
    for (int off = 1; off < 512; off <<= 1) {
        int v = (t >= off) ? tmp[t - off] : 0;
        __syncthreads();
        tmp[t] += v;
        __syncthreads();
    }
    if (t < nb) boff[t] = tmp[t] - orig;   // exclusive block offset
}

__global__ void scan3(const int* __restrict__ incl, const int* __restrict__ boff,
                      int* __restrict__ rowptr, int n) {
    int i = blockIdx.x * 256 + threadIdx.x;
    if (i < n) rowptr[i + 1] = incl[i] + boff[blockIdx.x];
    if (i == 0) rowptr[0] = 0;
}

__global__ void scatter_k(const int* __restrict__ src, const int* __restrict__ dst,
                          const float* __restrict__ dinv, const int* __restrict__ rowptr,
                          int* __restrict__ cursor, int* __restrict__ col,
                          float* __restrict__ wnorm, int E) {
    int e = blockIdx.x * blockDim.x + threadIdx.x;
    if (e >= E) return;
    int s = src[e], d = dst[e];
    int pos = atomicAdd(&cursor[d], 1);
    int idx = rowptr[d] + pos;
    col[idx] = s;
    wnorm[idx] = dinv[s] * dinv[d];
}

// ---------------- GEMM: [M,128] @ [128,128] (f32) ----------------

__global__ __launch_bounds__(256) void gemm128(const float* __restrict__ X,
                                               const float* __restrict__ W,
                                               float* __restrict__ H, int M) {
    __shared__ float As[32][32];
    __shared__ float Ws[32][128];
    int row0 = blockIdx.x * 32;
    int t = threadIdx.x;
    int c = t & 127, rg = t >> 7;   // 2 row-groups x 128 cols
    float acc[16];
#pragma unroll
    for (int r = 0; r < 16; ++r) acc[r] = 0.f;

    for (int k0 = 0; k0 < 128; k0 += 32) {
#pragma unroll
        for (int j = 0; j < 4; ++j) {
            int i = t + j * 256;
            int r = i >> 5, kk = i & 31;
            int rr = row0 + r; if (rr >= M) rr = M - 1;
            As[r][kk] = X[(size_t)rr * 128 + k0 + kk];
        }
#pragma unroll
        for (int j = 0; j < 16; ++j) {
            int i = t + j * 256;
            int kk = i >> 7, cc = i & 127;
            Ws[kk][cc] = W[(k0 + kk) * 128 + cc];
        }
        __syncthreads();
#pragma unroll
        for (int kk = 0; kk < 32; ++kk) {
            float wv = Ws[kk][c];
#pragma unroll
            for (int r = 0; r < 16; ++r) acc[r] += As[2 * r + rg][kk] * wv;
        }
        __syncthreads();
    }
#pragma unroll
    for (int r = 0; r < 16; ++r) {
        int row = row0 + 2 * r + rg;
        if (row < M) H[(size_t)row * 128 + c] = acc[r];
    }
}

// ---------------- aggregation (128-dim): one block per node ----------------

__global__ __launch_bounds__(128) void aggregate128(const float* __restrict__ H,
                                                    const float* __restrict__ dinv,
                                                    const int* __restrict__ rowptr,
                                                    const int* __restrict__ col,
                                                    const float* __restrict__ wnorm,
                                                    const float* __restrict__ bias,
                                                    float* __restrict__ Out, int relu) {
    int n = blockIdx.x;
    int f = threadIdx.x;
    float di = dinv[n];
    float acc = H[(size_t)n * 128 + f] * di * di;
    int e0 = rowptr[n], e1 = rowptr[n + 1];
    for (int e = e0; e < e1; ++e) {
        int s = col[e];
        float w = wnorm[e];
        acc += H[(size_t)s * 128 + f] * w;
    }
    acc += bias[f];
    if (relu) acc = fmaxf(acc, 0.0f);
    Out[(size_t)n * 128 + f] = acc;
}

// ---------------- layer-3 transform: [M,128] @ [128,2], wave per row ----------------

__global__ __launch_bounds__(256) void gemm_out2(const float* __restrict__ X,
                                                 const float* __restrict__ W3,
                                                 float* __restrict__ H3, int M) {
    int gtid = blockIdx.x * blockDim.x + threadIdx.x;
    int row = gtid >> 6;
    int lane = threadIdx.x & 63;
    if (row >= M) return;
    const float* xr = X + (size_t)row * 128;
    float x0 = xr[lane], x1 = xr[lane + 64];
    float a0 = x0 * W3[lane * 2 + 0] + x1 * W3[(lane + 64) * 2 + 0];
    float a1 = x0 * W3[lane * 2 + 1] + x1 * W3[(lane + 64) * 2 + 1];
    for (int off = 32; off; off >>= 1) {
        a0 += __shfl_down(a0, off);
        a1 += __shfl_down(a1, off);
    }
    if (lane == 0) {
        H3[(size_t)row * 2 + 0] = a0;
        H3[(size_t)row * 2 + 1] = a1;
    }
}

// ---------------- aggregation (2-dim): one thread per node ----------------

__global__ void aggregate2(const float* __restrict__ H3, const float* __restrict__ dinv,
                           const int* __restrict__ rowptr, const int* __restrict__ col,
                           const float* __restrict__ wnorm, const float* __restrict__ b3,
                           float* __restrict__ O3, int N) {
    int n = blockIdx.x * blockDim.x + threadIdx.x;
    if (n >= N) return;
    float di = dinv[n];
    float s0 = H3[(size_t)n * 2 + 0] * di * di;
    float s1 = H3[(size_t)n * 2 + 1] * di * di;
    int e1 = rowptr[n + 1];
    for (int e = rowptr[n]; e < e1; ++e) {
        int s = col[e];
        float w = wnorm[e];
        s0 += H3[(size_t)s * 2 + 0] * w;
        s1 += H3[(size_t)s * 2 + 1] * w;
    }
    O3[(size_t)n * 2 + 0] = s0 + b3[0];
    O3[(size_t)n * 2 + 1] = s1 + b3[1];
}

// ---------------- mean pool over batch segments ----------------

__global__ void pool_k(const float* __restrict__ O3, const int* __restrict__ batch,
                       float* __restrict__ pool, int N) {
    __shared__ float ls[64 * 3];
    for (int i = threadIdx.x; i < 192; i += blockDim.x) ls[i] = 0.f;
    __syncthreads();
    int n = blockIdx.x * blockDim.x + threadIdx.x;
    if (n < N) {
        int g = batch[n];
        atomicAdd(&ls[g * 3 + 0], O3[(size_t)n * 2 + 0]);
        atomicAdd(&ls[g * 3 + 1], O3[(size_t)n * 2 + 1]);
        atomicAdd(&ls[g * 3 + 2], 1.0f);
    }
    __syncthreads();
    for (int i = threadIdx.x; i < 192; i += blockDim.x)
        if (ls[i] != 0.f) atomicAdd(&pool[i], ls[i]);
}

__global__ void finalize_k(const float* __restrict__ pool, float* __restrict__ out) {
    int t = threadIdx.x;   // 128 threads: 64 graphs x 2
    if (t < 128) {
        int g = t >> 1, c = t & 1;
        out[t] = pool[g * 3 + c] / fmaxf(pool[g * 3 + 2], 1.0f);
    }
}

// ---------------- launch ----------------

extern "C" void kernel_launch(void* const* d_in, const int* in_sizes, int n_in,
                              void* d_out, int out_size, void* d_ws, size_t ws_size,
                              hipStream_t stream) {
    const float* x   = (const float*)d_in[0];
    const int*  edge = (const int*)d_in[1];
    const int*  batch= (const int*)d_in[2];
    const float* W1  = (const float*)d_in[3];
    const float* b1  = (const float*)d_in[4];
    const float* W2  = (const float*)d_in[5];
    const float* b2  = (const float*)d_in[6];
    const float* W3  = (const float*)d_in[7];
    const float* b3  = (const float*)d_in[8];
    float* out = (float*)d_out;

    int N = in_sizes[0] / 128;
    int E = in_sizes[1] / 2;
    const int* src = edge;
    const int* dst = edge + E;

    char* base = (char*)d_ws;
    size_t off = 0;
    auto alloc = [&](size_t bytes) -> void* {
        void* r = base + off;
        off = (off + bytes + 255) & ~(size_t)255;
        return r;
    };
    float* hA     = (float*)alloc((size_t)N * 128 * 4);
    float* hB     = (float*)alloc((size_t)N * 128 * 4);
    float* dinv   = (float*)alloc((size_t)N * 4);
    int*   cnt    = (int*)alloc((size_t)N * 4);
    int*   incl   = (int*)alloc((size_t)N * 4);
    int*   bsum   = (int*)alloc(1024 * 4);
    int*   boff   = (int*)alloc(1024 * 4);
    int*   rowptr = (int*)alloc((size_t)(N + 1) * 4);
    int*   cursor = (int*)alloc((size_t)N * 4);
    int*   col    = (int*)alloc((size_t)E * 4);
    float* wnorm  = (float*)alloc((size_t)E * 4);
    float* h3a    = (float*)alloc((size_t)N * 2 * 4);
    float* h3b    = (float*)alloc((size_t)N * 2 * 4);
    float* pool   = (float*)alloc(64 * 3 * 4);

    hipMemsetAsync(cnt, 0, (size_t)N * 4, stream);
    hipMemsetAsync(cursor, 0, (size_t)N * 4, stream);
    hipMemsetAsync(pool, 0, 64 * 3 * 4, stream);

    int nb = (N + 255) / 256;
    count_k<<<(E + 255) / 256, 256, 0, stream>>>(dst, cnt, E);
    dinv_k<<<nb, 256, 0, stream>>>(cnt, dinv, N);
    scan1<<<nb, 256, 0, stream>>>(cnt, incl, bsum, N);
    scan2<<<1, 512, 0, stream>>>(bsum, boff, nb);
    scan3<<<nb, 256, 0, stream>>>(incl, boff, rowptr, N);
    scatter_k<<<(E + 255) / 256, 256, 0, stream>>>(src, dst, dinv, rowptr, cursor, col, wnorm, E);

    // layer 1
    gemm128<<<(N + 31) / 32, 256, 0, stream>>>(x, W1, hA, N);
    aggregate128<<<N, 128, 0, stream>>>(hA, dinv, rowptr, col, wnorm, b1, hB, 1);
    // layer 2
    gemm128<<<(N + 31) / 32, 256, 0, stream>>>(hB, W2, hA, N);
    aggregate128<<<N, 128, 0, stream>>>(hA, dinv, rowptr, col, wnorm, b2, hB, 1);
    // layer 3 (transform to 2 dims first, then aggregate)
    gemm_out2<<<(N * 64 + 255) / 256, 256, 0, stream>>>(hB, W3, h3a, N);
    aggregate2<<<(N + 255) / 256, 256, 0, stream>>>(h3a, dinv, rowptr, col, wnorm, b3, h3b, N);
    // pool
    pool_k<<<(N + 255) / 256, 256, 0, stream>>>(h3b, batch, pool, N);
    finalize_k<<<1, 128, 0, stream>>>(pool, out);
}

// Round 2
// 566.687 us; speedup vs baseline: 1.5050x; 1.5050x over previous
//
#include <hip/hip_runtime.h>

// ---------------- degree / CSR construction ----------------

__global__ void count_k(const int* __restrict__ dst, int* __restrict__ cnt, int E) {
    int e = blockIdx.x * blockDim.x + threadIdx.x;
    if (e < E) atomicAdd(&cnt[dst[e]], 1);
}

__global__ void dinv_k(const int* __restrict__ cnt, float* __restrict__ dinv, int N) {
    int i = blockIdx.x * blockDim.x + threadIdx.x;
    if (i < N) dinv[i] = rsqrtf((float)cnt[i] + 1.0f);
}

__global__ void scan1(const int* __restrict__ cnt, int* __restrict__ incl,
                      int* __restrict__ bsum, int n) {
    __shared__ int tmp[256];
    int t = threadIdx.x;
    int gid = blockIdx.x * 256 + t;
    tmp[t] = (gid < n) ? cnt[gid] : 0;
    __syncthreads();
    for (int off = 1; off < 256; off <<= 1) {
        int v = (t >= off) ? tmp[t - off] : 0;
        __syncthreads();
        tmp[t] += v;
        __syncthreads();
    }
    if (gid < n) incl[gid] = tmp[t];
    if (t == 255) bsum[blockIdx.x] = tmp[255];
}

__global__ void scan2(const int* __restrict__ bsum, int* __restrict__ boff, int nb) {
    __shared__ int tmp[512];
    int t = threadIdx.x;
    int orig = (t < nb) ? bsum[t] : 0;
    tmp[t] = orig;
    __syncthreads();
    for (int off = 1; off < 512; off <<= 1) {
        int v = (t >= off) ? tmp[t - off] : 0;
        __syncthreads();
        tmp[t] += v;
        __syncthreads();
    }
    if (t < nb) boff[t] = tmp[t] - orig;   // exclusive block offset
}

__global__ void scan3(const int* __restrict__ incl, const int* __restrict__ boff,
                      int* __restrict__ rowptr, int n) {
    int i = blockIdx.x * 256 + threadIdx.x;
    if (i < n) rowptr[i + 1] = incl[i] + boff[blockIdx.x];
    if (i == 0) rowptr[0] = 0;
}

__global__ void scatter_k(const int* __restrict__ src, const int* __restrict__ dst,
                          const float* __restrict__ dinv, const int* __restrict__ rowptr,
                          int* __restrict__ cursor, int* __restrict__ col,
                          float* __restrict__ wnorm, int E) {
    int e = blockIdx.x * blockDim.x + threadIdx.x;
    if (e >= E) return;
    int s = src[e], d = dst[e];
    int pos = atomicAdd(&cursor[d], 1);
    int idx = rowptr[d] + pos;
    col[idx] = s;
    wnorm[idx] = dinv[s] * dinv[d];
}

// ---------------- GEMM: [M,128] @ [128,128] (f32), 128x128 tile, 8x8 reg block ----

__global__ __launch_bounds__(256) void gemm128(const float* __restrict__ X,
                                               const float* __restrict__ W,
                                               float* __restrict__ H, int M) {
    __shared__ float Xs[32][132];   // transposed [kk][row], padded
    __shared__ float Ws[32][128];   // [kk][col]
    int row0 = blockIdx.x * 128;
    int t = threadIdx.x;
    int tx = t & 15, ty = t >> 4;
    int c0 = tx * 8, r0 = ty * 8;
    float acc[8][8];
#pragma unroll
    for (int i = 0; i < 8; ++i)
#pragma unroll
        for (int j = 0; j < 8; ++j) acc[i][j] = 0.f;

    int lr = t & 7;        // lane-in-row for loads (8 lanes x float4 = 32 floats)
    int rbase = t >> 3;    // 0..31

    for (int k0 = 0; k0 < 128; k0 += 32) {
        // stage X tile (rows row0..+127, k k0..+31), transposed into Xs
#pragma unroll
        for (int p = 0; p < 4; ++p) {
            int r = rbase + p * 32;
            int rr = row0 + r; if (rr >= M) rr = M - 1;
            const float4 v = *(const float4*)&X[(size_t)rr * 128 + k0 + lr * 4];
            Xs[lr * 4 + 0][r] = v.x;
            Xs[lr * 4 + 1][r] = v.y;
            Xs[lr * 4 + 2][r] = v.z;
            Xs[lr * 4 + 3][r] = v.w;
        }
        // stage W tile (k k0..+31, all 128 cols)
#pragma unroll
        for (int p = 0; p < 4; ++p) {
            int cc = lr * 4 + p * 32;
            *(float4*)&Ws[rbase][cc] = *(const float4*)&W[(size_t)(k0 + rbase) * 128 + cc];
        }
        __syncthreads();
#pragma unroll
        for (int kk = 0; kk < 32; ++kk) {
            float xa[8], wb[8];
            *(float4*)&xa[0] = *(const float4*)&Xs[kk][r0];
            *(float4*)&xa[4] = *(const float4*)&Xs[kk][r0 + 4];
            *(float4*)&wb[0] = *(const float4*)&Ws[kk][c0];
            *(float4*)&wb[4] = *(const float4*)&Ws[kk][c0 + 4];
#pragma unroll
            for (int i = 0; i < 8; ++i)
#pragma unroll
                for (int j = 0; j < 8; ++j)
                    acc[i][j] += xa[i] * wb[j];
        }
        __syncthreads();
    }
#pragma unroll
    for (int i = 0; i < 8; ++i) {
        int row = row0 + r0 + i;
        if (row < M) {
            *(float4*)&H[(size_t)row * 128 + c0]     = *(float4*)&acc[i][0];
            *(float4*)&H[(size_t)row * 128 + c0 + 4] = *(float4*)&acc[i][4];
        }
    }
}

// ---------------- aggregation (128-dim): one WAVE per node, float2 lanes ------

__global__ __launch_bounds__(256) void aggregate128(const float2* __restrict__ H2,
                                                    const float* __restrict__ dinv,
                                                    const int* __restrict__ rowptr,
                                                    const int* __restrict__ col,
                                                    const float* __restrict__ wnorm,
                                                    const float2* __restrict__ bias2,
                                                    float2* __restrict__ Out2,
                                                    int relu, int N) {
    int n = blockIdx.x * 4 + (threadIdx.x >> 6);
    if (n >= N) return;
    int f = threadIdx.x & 63;
    float di = dinv[n];
    float sl = di * di;
    float2 h = H2[(size_t)n * 64 + f];
    float ax = h.x * sl, ay = h.y * sl;
    int e0 = rowptr[n], e1 = rowptr[n + 1];
    int e = e0;
    for (; e + 4 <= e1; e += 4) {
        int s0 = col[e], s1 = col[e + 1], s2 = col[e + 2], s3 = col[e + 3];
        float w0 = wnorm[e], w1 = wnorm[e + 1], w2 = wnorm[e + 2], w3 = wnorm[e + 3];
        float2 v0 = H2[(size_t)s0 * 64 + f];
        float2 v1 = H2[(size_t)s1 * 64 + f];
        float2 v2 = H2[(size_t)s2 * 64 + f];
        float2 v3 = H2[(size_t)s3 * 64 + f];
        ax += v0.x * w0 + v1.x * w1 + v2.x * w2 + v3.x * w3;
        ay += v0.y * w0 + v1.y * w1 + v2.y * w2 + v3.y * w3;
    }
    for (; e < e1; ++e) {
        int s = col[e];
        float w = wnorm[e];
        float2 v = H2[(size_t)s * 64 + f];
        ax += v.x * w;
        ay += v.y * w;
    }
    float2 b = bias2[f];
    ax += b.x; ay += b.y;
    if (relu) { ax = fmaxf(ax, 0.f); ay = fmaxf(ay, 0.f); }
    float2 o; o.x = ax; o.y = ay;
    Out2[(size_t)n * 64 + f] = o;
}

// ---------------- layer-3 transform: [M,128] @ [128,2], wave per row ----------

__global__ __launch_bounds__(256) void gemm_out2(const float* __restrict__ X,
                                                 const float* __restrict__ W3,
                                                 float* __restrict__ H3, int M) {
    int gtid = blockIdx.x * blockDim.x + threadIdx.x;
    int row = gtid >> 6;
    int lane = threadIdx.x & 63;
    if (row >= M) return;
    const float* xr = X + (size_t)row * 128;
    float x0 = xr[lane], x1 = xr[lane + 64];
    float a0 = x0 * W3[lane * 2 + 0] + x1 * W3[(lane + 64) * 2 + 0];
    float a1 = x0 * W3[lane * 2 + 1] + x1 * W3[(lane + 64) * 2 + 1];
    for (int off = 32; off; off >>= 1) {
        a0 += __shfl_down(a0, off);
        a1 += __shfl_down(a1, off);
    }
    if (lane == 0) {
        H3[(size_t)row * 2 + 0] = a0;
        H3[(size_t)row * 2 + 1] = a1;
    }
}

// ---------------- aggregation (2-dim): one thread per node --------------------

__global__ void aggregate2(const float* __restrict__ H3, const float* __restrict__ dinv,
                           const int* __restrict__ rowptr, const int* __restrict__ col,
                           const float* __restrict__ wnorm, const float* __restrict__ b3,
                           float* __restrict__ O3, int N) {
    int n = blockIdx.x * blockDim.x + threadIdx.x;
    if (n >= N) return;
    float di = dinv[n];
    float s0 = H3[(size_t)n * 2 + 0] * di * di;
    float s1 = H3[(size_t)n * 2 + 1] * di * di;
    int e1 = rowptr[n + 1];
    for (int e = rowptr[n]; e < e1; ++e) {
        int s = col[e];
        float w = wnorm[e];
        s0 += H3[(size_t)s * 2 + 0] * w;
        s1 += H3[(size_t)s * 2 + 1] * w;
    }
    O3[(size_t)n * 2 + 0] = s0 + b3[0];
    O3[(size_t)n * 2 + 1] = s1 + b3[1];
}

// ---------------- mean pool over batch segments --------------------------------

__global__ void pool_k(const float* __restrict__ O3, const int* __restrict__ batch,
                       float* __restrict__ pool, int N) {
    __shared__ float ls[64 * 3];
    for (int i = threadIdx.x; i < 192; i += blockDim.x) ls[i] = 0.f;
    __syncthreads();
    int n = blockIdx.x * blockDim.x + threadIdx.x;
    if (n < N) {
        int g = batch[n];
        atomicAdd(&ls[g * 3 + 0], O3[(size_t)n * 2 + 0]);
        atomicAdd(&ls[g * 3 + 1], O3[(size_t)n * 2 + 1]);
        atomicAdd(&ls[g * 3 + 2], 1.0f);
    }
    __syncthreads();
    for (int i = threadIdx.x; i < 192; i += blockDim.x)
        if (ls[i] != 0.f) atomicAdd(&pool[i], ls[i]);
}

__global__ void finalize_k(const float* __restrict__ pool, float* __restrict__ out) {
    int t = threadIdx.x;   // 128 threads: 64 graphs x 2
    if (t < 128) {
        int g = t >> 1, c = t & 1;
        out[t] = pool[g * 3 + c] / fmaxf(pool[g * 3 + 2], 1.0f);
    }
}

// ---------------- launch --------------------------------------------------------

extern "C" void kernel_launch(void* const* d_in, const int* in_sizes, int n_in,
                              void* d_out, int out_size, void* d_ws, size_t ws_size,
                              hipStream_t stream) {
    const float* x   = (const float*)d_in[0];
    const int*  edge = (const int*)d_in[1];
    const int*  batch= (const int*)d_in[2];
    const float* W1  = (const float*)d_in[3];
    const float* b1  = (const float*)d_in[4];
    const float* W2  = (const float*)d_in[5];
    const float* b2  = (const float*)d_in[6];
    const float* W3  = (const float*)d_in[7];
    const float* b3  = (const float*)d_in[8];
    float* out = (float*)d_out;

    int N = in_sizes[0] / 128;
    int E = in_sizes[1] / 2;
    const int* src = edge;
    const int* dst = edge + E;

    char* base = (char*)d_ws;
    size_t off = 0;
    auto alloc = [&](size_t bytes) -> void* {
        void* r = base + off;
        off = (off + bytes + 255) & ~(size_t)255;
        return r;
    };
    float* hA     = (float*)alloc((size_t)N * 128 * 4);
    float* hB     = (float*)alloc((size_t)N * 128 * 4);
    float* dinv   = (float*)alloc((size_t)N * 4);
    int*   cnt    = (int*)alloc((size_t)N * 4);
    int*   incl   = (int*)alloc((size_t)N * 4);
    int*   bsum   = (int*)alloc(1024 * 4);
    int*   boff   = (int*)alloc(1024 * 4);
    int*   rowptr = (int*)alloc((size_t)(N + 1) * 4);
    int*   cursor = (int*)alloc((size_t)N * 4);
    int*   col    = (int*)alloc((size_t)E * 4);
    float* wnorm  = (float*)alloc((size_t)E * 4);
    float* h3a    = (float*)alloc((size_t)N * 2 * 4);
    float* h3b    = (float*)alloc((size_t)N * 2 * 4);
    float* pool   = (float*)alloc(64 * 3 * 4);

    hipMemsetAsync(cnt, 0, (size_t)N * 4, stream);
    hipMemsetAsync(cursor, 0, (size_t)N * 4, stream);
    hipMemsetAsync(pool, 0, 64 * 3 * 4, stream);

    int nb = (N + 255) / 256;
    count_k<<<(E + 255) / 256, 256, 0, stream>>>(dst, cnt, E);
    dinv_k<<<nb, 256, 0, stream>>>(cnt, dinv, N);
    scan1<<<nb, 256, 0, stream>>>(cnt, incl, bsum, N);
    scan2<<<1, 512, 0, stream>>>(bsum, boff, nb);
    scan3<<<nb, 256, 0, stream>>>(incl, boff, rowptr, N);
    scatter_k<<<(E + 255) / 256, 256, 0, stream>>>(src, dst, dinv, rowptr, cursor, col, wnorm, E);

    int gb = (N + 127) / 128;   // gemm blocks
    int ab = (N + 3) / 4;       // aggregate blocks (4 nodes/block, wave per node)

    // layer 1
    gemm128<<<gb, 256, 0, stream>>>(x, W1, hA, N);
    aggregate128<<<ab, 256, 0, stream>>>((const float2*)hA, dinv, rowptr, col, wnorm,
                                         (const float2*)b1, (float2*)hB, 1, N);
    // layer 2
    gemm128<<<gb, 256, 0, stream>>>(hB, W2, hA, N);
    aggregate128<<<ab, 256, 0, stream>>>((const float2*)hA, dinv, rowptr, col, wnorm,
                                         (const float2*)b2, (float2*)hB, 1, N);
    // layer 3 (transform to 2 dims first, then aggregate)
    gemm_out2<<<(N * 64 + 255) / 256, 256, 0, stream>>>(hB, W3, h3a, N);
    aggregate2<<<(N + 255) / 256, 256, 0, stream>>>(h3a, dinv, rowptr, col, wnorm, b3, h3b, N);
    // pool
    pool_k<<<(N + 255) / 256, 256, 0, stream>>>(h3b, batch, pool, N);
    finalize_k<<<1, 128, 0, stream>>>(pool, out);
}